// Round 7
// baseline (645.028 us; speedup 1.0000x reference)
//
#include <hip/hip_runtime.h>
#include <hip/hip_bf16.h>

// Elman RNN (relu), B=4096 T=4096 H=32, fp32 in/out.
// h_new[j] = relu( sum_k W_hh[j,k] h[k] + x*W_ih[j] + b_ih[j]+b_hh[j] )
//
// R6 post-mortem: DPP-fused MACs occupy ~4.4 cyc/instr of VALU pipe (measured
// across R3/R4/R6); R6 is DPP-throughput bound at 81% VALUBusy. Escape: do the
// 32x32 matvec on the MFMA pipe. One wave owns 16 batches:
//   D1[16,16] = mfma_16x16x32_bf16(A1=W_hh[0:16,:],  B=H[32,16], C1)
//   D2[16,16] = mfma_16x16x32_bf16(A2=W_hh[16:32,:], B=H[32,16], C2)
// with C[m,n] = x[n,t]*W_ih[m] + (b_ih+b_hh)[m] built by 8 plain fmas.
// Layouts (m89/m120-verified): A[m=lane&15][k=(lane>>4)*8+j];
// B[k][n]: n=lane&15, k=(lane>>4)*8+j; C/D: n=lane&15, m=(lane>>4)*4+r.
// D->next-B is a quad permutation: relu -> pack bf16 pairs -> LDS round-trip
// (2x ds_write_b64 + 1x ds_read_b128, stride-20 words to spread banks; same
// wave, in-order DS pipe => no barrier).
// Precision: h carried in bf16 (~2e-3 rel). The checked output is
// hn @ W_reg (32-term average) => error ~1e-4..1e-3 << 8.2e-3 threshold;
// final step's h used in fp32 for the projection.
// 256 blocks x 64 thr = 256 waves = 1 wave/CU; serial chain latency bound.

#define HSZ 32

typedef short short8 __attribute__((ext_vector_type(8)));
typedef float f32x4 __attribute__((ext_vector_type(4)));

__device__ __forceinline__ unsigned short f2bf(float f) {  // RNE f32->bf16
  union { float f; unsigned u; } v; v.f = f;
  unsigned u = v.u;
  return (unsigned short)((u + 0x7FFFu + ((u >> 16) & 1u)) >> 16);
}

__device__ __forceinline__ unsigned pk2(float lo, float hi) {  // (lo,hi)->bf16x2
  __hip_bfloat162 h2 = __float22bfloat162_rn(make_float2(lo, hi));
  union { __hip_bfloat162 h; unsigned u; } c; c.h = h2;
  return c.u;  // lo in low 16 bits
}

__global__ __attribute__((amdgpu_flat_work_group_size(64, 64),
                          amdgpu_waves_per_eu(1, 1)))
void rnn_reg_kernel(
    const float* __restrict__ x, const float* __restrict__ h_init,
    const float* __restrict__ W_ih, const float* __restrict__ W_hh,
    const float* __restrict__ b_ih, const float* __restrict__ b_hh,
    const float* __restrict__ W_reg, const float* __restrict__ b_reg,
    float* __restrict__ out, int T) {
  const int lane = threadIdx.x;       // 0..63
  const int lo4  = lane & 15;         // MFMA column n (batch) / A row m
  const int q    = lane >> 4;         // quad 0..3
  const int bg   = blockIdx.x * 16 + lo4;   // this lane's batch (B role)

  // LDS: per batch-column n, 16 words of bf16x2 (unit u at word u>>1),
  // stride 20 words (coprime-ish with 32 banks; keeps uint4 reads 16B-aligned)
  __shared__ unsigned lds[16 * 20];

  // Static A fragments: A[m=lo4][k=8q+j] = W_hh[row m, col k]
  short8 A1, A2;
#pragma unroll
  for (int j = 0; j < 8; ++j) {
    A1[j] = (short)f2bf(W_hh[lo4 * HSZ + 8 * q + j]);
    A2[j] = (short)f2bf(W_hh[(16 + lo4) * HSZ + 8 * q + j]);
  }

  // C-build constants for output rows m = 4q+r (D1) and 16+4q+r (D2)
  float wih1[4], wih2[4], bia1[4], bia2[4];
#pragma unroll
  for (int r = 0; r < 4; ++r) {
    int m1 = 4 * q + r, m2 = 16 + 4 * q + r;
    wih1[r] = W_ih[m1]; bia1[r] = b_ih[m1] + b_hh[m1];
    wih2[r] = W_ih[m2]; bia2[r] = b_ih[m2] + b_hh[m2];
  }

  // Initial B fragment from h_init: B[k=8q+j][n=lo4]
  short8 bfrag;
#pragma unroll
  for (int j = 0; j < 8; ++j)
    bfrag[j] = (short)f2bf(h_init[(size_t)bg * HSZ + 8 * q + j]);

  const int wb = lo4 * 20 + 2 * q;  // write words (D1); +8 for D2
  const int rb = lo4 * 20 + 4 * q;  // read words (B frag)

  float e1[4], e2[4];               // relu'd state (fp32), loop-carried

#define STEP(xv)                                                           \
  do {                                                                     \
    f32x4 c1, c2;                                                          \
    _Pragma("unroll") for (int r = 0; r < 4; ++r) {                        \
      c1[r] = fmaf((xv), wih1[r], bia1[r]);                                \
      c2[r] = fmaf((xv), wih2[r], bia2[r]);                                \
    }                                                                      \
    f32x4 d1 = __builtin_amdgcn_mfma_f32_16x16x32_bf16(A1, bfrag, c1, 0, 0, 0); \
    f32x4 d2 = __builtin_amdgcn_mfma_f32_16x16x32_bf16(A2, bfrag, c2, 0, 0, 0); \
    _Pragma("unroll") for (int r = 0; r < 4; ++r) {                        \
      e1[r] = fmaxf(d1[r], 0.f);                                           \
      e2[r] = fmaxf(d2[r], 0.f);                                           \
    }                                                                      \
    uint2 w1; w1.x = pk2(e1[0], e1[1]); w1.y = pk2(e1[2], e1[3]);          \
    uint2 w2; w2.x = pk2(e2[0], e2[1]); w2.y = pk2(e2[2], e2[3]);          \
    *(uint2*)&lds[wb] = w1;      /* units 4q..4q+3   -> words 2q,2q+1 */   \
    *(uint2*)&lds[wb + 8] = w2;  /* units 16+4q..+3  -> words 8+2q,.. */   \
    uint4 rr = *(uint4*)&lds[rb]; /* units 8q..8q+7 -> words 4q..4q+3 */   \
    union { uint4 u; short8 s; } cv; cv.u = rr;                            \
    bfrag = cv.s;                                                          \
  } while (0)

  // x feed: lane reads its batch's row; quads are 4x redundant (L1 absorbs).
  // 2-deep float4 rotation = 8-step prefetch distance.
  const float4* xr = (const float4*)(x + (size_t)bg * (size_t)T);
  const int last = T / 4 - 1;
  float4 xa = xr[0], xb = xr[1];

#pragma unroll 1
  for (int t = 0; t < T; t += 8) {
    int i0 = (t >> 2) + 2; if (i0 > last) i0 = last;
    int i1 = (t >> 2) + 3; if (i1 > last) i1 = last;
    float4 na = xr[i0];
    float4 nb = xr[i1];
    STEP(xa.x); STEP(xa.y); STEP(xa.z); STEP(xa.w);
    STEP(xb.x); STEP(xb.y); STEP(xb.z); STEP(xb.w);
    xa = na; xb = nb;
  }

  // out[b_n] = sum_u h[u]*W_reg[u] + b_reg. Lane (q,n) holds units 4q+r
  // and 16+4q+r of batch n in fp32 (e1/e2). Reduce across quads.
  float v = 0.f;
#pragma unroll
  for (int r = 0; r < 4; ++r) {
    v = fmaf(e1[r], W_reg[4 * q + r], v);
    v = fmaf(e2[r], W_reg[16 + 4 * q + r], v);
  }
  v += __shfl_xor(v, 16, 64);
  v += __shfl_xor(v, 32, 64);
  if (q == 0) out[bg] = v + b_reg[0];
}

extern "C" void kernel_launch(void* const* d_in, const int* in_sizes, int n_in,
                              void* d_out, int out_size, void* d_ws, size_t ws_size,
                              hipStream_t stream) {
  const float* x      = (const float*)d_in[0];
  const float* h_init = (const float*)d_in[1];
  const float* W_ih   = (const float*)d_in[2];
  const float* W_hh   = (const float*)d_in[3];
  const float* b_ih   = (const float*)d_in[4];
  const float* b_hh   = (const float*)d_in[5];
  const float* W_reg  = (const float*)d_in[6];
  const float* b_reg  = (const float*)d_in[7];
  float* out = (float*)d_out;

  const int B = in_sizes[1] / HSZ;   // 4096
  const int T = in_sizes[0] / B;     // 4096
  const int grid = B / 16;           // 16 batches per wave/block

  rnn_reg_kernel<<<dim3(grid), dim3(64), 0, stream>>>(
      x, h_init, W_ih, W_hh, b_ih, b_hh, W_reg, b_reg, out, T);
}

// Round 8
// 589.208 us; speedup vs baseline: 1.0947x; 1.0947x over previous
//
#include <hip/hip_runtime.h>
#include <hip/hip_bf16.h>

// Elman RNN (relu), B=4096 T=4096 H=32, fp32 in/out.
// h_new[j] = relu( sum_k W_hh[j,k] h[k] + x*W_ih[j] + b_ih[j]+b_hh[j] )
//
// R7 validated MFMA fragment layouts end-to-end (absmax = bf16 rounding):
//   A[m=lane&15][k=8*quad+j]; B[k=8*quad+i][n=lane&15]; D: n=lane&15, m=4*quad+r.
// R7's wall was the D->B layout transform through LDS (~180 cyc of a 337-cyc
// chain; ds_read latency ~120 + in-order DS behind 2 writes + bank conflicts).
//
// R8: choose the A-row permutation so D-layout == next-step B-layout:
//   A1 row m computes unit u1(m) = 8*(m>>2) + (m&3)   (units {8q+r})
//   A2 row m computes unit u2(m) = u1(m) + 4          (units {8q+4+r})
// => lane (batch n, quad q) exits with units 8q..8q+7 of its batch:
//    exactly the B fragment. Transform = relu + pack, ALL lane-local.
// Chain: mfma -> v_max x8 -> v_cvt_pk_bf16 x4 -> mfma. No LDS, no cross-lane.
// 256 blocks x 64 thr = 1 wave/CU; 16 batches per wave.

#define HSZ 32

typedef short short8 __attribute__((ext_vector_type(8)));
typedef float f32x4 __attribute__((ext_vector_type(4)));

__device__ __forceinline__ unsigned short f2bf(float f) {  // RNE f32->bf16
  union { float f; unsigned u; } v; v.f = f;
  unsigned u = v.u;
  return (unsigned short)((u + 0x7FFFu + ((u >> 16) & 1u)) >> 16);
}

__device__ __forceinline__ unsigned pk2(float lo, float hi) {  // (lo,hi)->bf16x2
  __hip_bfloat162 h2 = __float22bfloat162_rn(make_float2(lo, hi));
  union { __hip_bfloat162 h; unsigned u; } c; c.h = h2;
  return c.u;  // lo in low 16 bits
}

__global__ __attribute__((amdgpu_flat_work_group_size(64, 64),
                          amdgpu_waves_per_eu(1, 1)))
void rnn_reg_kernel(
    const float* __restrict__ x, const float* __restrict__ h_init,
    const float* __restrict__ W_ih, const float* __restrict__ W_hh,
    const float* __restrict__ b_ih, const float* __restrict__ b_hh,
    const float* __restrict__ W_reg, const float* __restrict__ b_reg,
    float* __restrict__ out, int T) {
  const int lane = threadIdx.x;             // 0..63
  const int lo4  = lane & 15;               // batch column n / A row m
  const int q    = lane >> 4;               // quad 0..3
  const int bg   = blockIdx.x * 16 + lo4;   // this lane's batch

  // Permuted A rows: row m of A1 is W_hh[u1(m)], row m of A2 is W_hh[u2(m)]
  const int u1m = 8 * (lo4 >> 2) + (lo4 & 3);  // u1(lo4)
  short8 A1, A2;
#pragma unroll
  for (int j = 0; j < 8; ++j) {
    A1[j] = (short)f2bf(W_hh[u1m * HSZ + 8 * q + j]);
    A2[j] = (short)f2bf(W_hh[(u1m + 4) * HSZ + 8 * q + j]);
  }

  // C-build constants: D1 reg r is unit 8q+r, D2 reg r is unit 8q+4+r
  float wih1[4], wih2[4], bia1[4], bia2[4];
#pragma unroll
  for (int r = 0; r < 4; ++r) {
    int m1 = 8 * q + r, m2 = 8 * q + 4 + r;
    wih1[r] = W_ih[m1]; bia1[r] = b_ih[m1] + b_hh[m1];
    wih2[r] = W_ih[m2]; bia2[r] = b_ih[m2] + b_hh[m2];
  }

  // Initial B fragment from h_init: B[k=8q+i][n=lo4]
  short8 bfrag;
#pragma unroll
  for (int i = 0; i < 8; ++i)
    bfrag[i] = (short)f2bf(h_init[(size_t)bg * HSZ + 8 * q + i]);

  float e1[4], e2[4];  // relu'd state (fp32): units 8q+r / 8q+4+r, loop-carried

#define STEP(xv)                                                           \
  do {                                                                     \
    f32x4 c1, c2;                                                          \
    _Pragma("unroll") for (int r = 0; r < 4; ++r) {                        \
      c1[r] = fmaf((xv), wih1[r], bia1[r]);                                \
      c2[r] = fmaf((xv), wih2[r], bia2[r]);                                \
    }                                                                      \
    f32x4 d1 = __builtin_amdgcn_mfma_f32_16x16x32_bf16(A1, bfrag, c1, 0, 0, 0); \
    f32x4 d2 = __builtin_amdgcn_mfma_f32_16x16x32_bf16(A2, bfrag, c2, 0, 0, 0); \
    _Pragma("unroll") for (int r = 0; r < 4; ++r) {                        \
      e1[r] = fmaxf(d1[r], 0.f);                                           \
      e2[r] = fmaxf(d2[r], 0.f);                                           \
    }                                                                      \
    union { uint4 u; short8 s; } cv;                                       \
    cv.u.x = pk2(e1[0], e1[1]);  /* units 8q+0,1 */                        \
    cv.u.y = pk2(e1[2], e1[3]);  /* units 8q+2,3 */                        \
    cv.u.z = pk2(e2[0], e2[1]);  /* units 8q+4,5 */                        \
    cv.u.w = pk2(e2[2], e2[3]);  /* units 8q+6,7 */                        \
    bfrag = cv.s;                                                          \
  } while (0)

  // x feed: lane reads its batch's row; quads 4x redundant (L1 absorbs).
  // 2-deep float4 rotation = 8-step prefetch distance.
  const float4* xr = (const float4*)(x + (size_t)bg * (size_t)T);
  const int last = T / 4 - 1;
  float4 xa = xr[0], xb = xr[1];

#pragma unroll 1
  for (int t = 0; t < T; t += 8) {
    int i0 = (t >> 2) + 2; if (i0 > last) i0 = last;
    int i1 = (t >> 2) + 3; if (i1 > last) i1 = last;
    float4 na = xr[i0];
    float4 nb = xr[i1];
    STEP(xa.x); STEP(xa.y); STEP(xa.z); STEP(xa.w);
    STEP(xb.x); STEP(xb.y); STEP(xb.z); STEP(xb.w);
    xa = na; xb = nb;
  }

  // out[bg] = sum_u h[u]*W_reg[u] + b_reg; lane (q,n) holds units 8q+r (e1)
  // and 8q+4+r (e2) in fp32. Reduce across quads (lanes n, n+16, n+32, n+48).
  float v = 0.f;
#pragma unroll
  for (int r = 0; r < 4; ++r) {
    v = fmaf(e1[r], W_reg[8 * q + r], v);
    v = fmaf(e2[r], W_reg[8 * q + 4 + r], v);
  }
  v += __shfl_xor(v, 16, 64);
  v += __shfl_xor(v, 32, 64);
  if (q == 0) out[bg] = v + b_reg[0];
}

extern "C" void kernel_launch(void* const* d_in, const int* in_sizes, int n_in,
                              void* d_out, int out_size, void* d_ws, size_t ws_size,
                              hipStream_t stream) {
  const float* x      = (const float*)d_in[0];
  const float* h_init = (const float*)d_in[1];
  const float* W_ih   = (const float*)d_in[2];
  const float* W_hh   = (const float*)d_in[3];
  const float* b_ih   = (const float*)d_in[4];
  const float* b_hh   = (const float*)d_in[5];
  const float* W_reg  = (const float*)d_in[6];
  const float* b_reg  = (const float*)d_in[7];
  float* out = (float*)d_out;

  const int B = in_sizes[1] / HSZ;   // 4096
  const int T = in_sizes[0] / B;     // 4096
  const int grid = B / 16;           // 16 batches per wave/block

  rnn_reg_kernel<<<dim3(grid), dim3(64), 0, stream>>>(
      x, h_init, W_ih, W_hh, b_ih, b_hh, W_reg, b_reg, out, T);
}

// Round 10
// 522.710 us; speedup vs baseline: 1.2340x; 1.1272x over previous
//
#include <hip/hip_runtime.h>

// Elman RNN (relu), B=4096 T=4096 H=32, fp32 in/out.
// h_new[j] = relu( sum_k W_hh[j,k] h[k] + x*W_ih[j] + b_ih[j]+b_hh[j] )
//
// R8 post-mortem: VALUBusy is CU-averaged over 4 SIMDs; at 1 wave/CU the
// wave's SIMD was ~72% busy -> issue-bound. The consumer: software bf16-RNE
// packing (~44 VALU/step; gfx950 f32->bf16 pack is not hw-single-instr here).
// R9: carry the state in FP16. mfma_f32_16x16x32_f16 has the identical
// fragment layout (C/D layout is dtype-independent), so R8's A-row
// permutation (D-layout == next B-layout, zero cross-lane transform) is
// unchanged. Epilogue tail = 8x v_max_f32 + 4x v_cvt_pkrtz_f16_f32 (hw,
// one per pair). f16 (10 mantissa bits) beats bf16-RNE even with RTZ.
//   A1 row m computes unit u1(m)=8*(m>>2)+(m&3); A2 row m -> u1(m)+4.
//   Lane (batch n=lane&15, quad q) exits with units 8q..8q+7 = B fragment.
// 256 blocks x 64 thr = 1 wave/CU, 16 batches per wave.
// (R9 fix: cvt_pkrtz returns __fp16x2, not _Float16x2 — union uses __fp16.)

#define HSZ 32

typedef _Float16 half8 __attribute__((ext_vector_type(8)));
typedef __fp16 fp16x2 __attribute__((ext_vector_type(2)));
typedef float f32x4 __attribute__((ext_vector_type(4)));

__global__ __attribute__((amdgpu_flat_work_group_size(64, 64),
                          amdgpu_waves_per_eu(1, 1)))
void rnn_reg_kernel(
    const float* __restrict__ x, const float* __restrict__ h_init,
    const float* __restrict__ W_ih, const float* __restrict__ W_hh,
    const float* __restrict__ b_ih, const float* __restrict__ b_hh,
    const float* __restrict__ W_reg, const float* __restrict__ b_reg,
    float* __restrict__ out, int T) {
  const int lane = threadIdx.x;             // 0..63
  const int lo4  = lane & 15;               // batch column n / A row m
  const int q    = lane >> 4;               // quad 0..3
  const int bg   = blockIdx.x * 16 + lo4;   // this lane's batch

  // Permuted A rows: row m of A1 is W_hh[u1(m)], row m of A2 is W_hh[u1(m)+4]
  const int u1m = 8 * (lo4 >> 2) + (lo4 & 3);
  half8 A1, A2;
#pragma unroll
  for (int j = 0; j < 8; ++j) {
    A1[j] = (_Float16)W_hh[u1m * HSZ + 8 * q + j];          // v_cvt_f16_f32 RNE
    A2[j] = (_Float16)W_hh[(u1m + 4) * HSZ + 8 * q + j];
  }

  // C-build constants: D1 reg r is unit 8q+r, D2 reg r is unit 8q+4+r
  float wih1[4], wih2[4], bia1[4], bia2[4];
#pragma unroll
  for (int r = 0; r < 4; ++r) {
    int m1 = 8 * q + r, m2 = 8 * q + 4 + r;
    wih1[r] = W_ih[m1]; bia1[r] = b_ih[m1] + b_hh[m1];
    wih2[r] = W_ih[m2]; bia2[r] = b_ih[m2] + b_hh[m2];
  }

  // Initial B fragment from h_init: B[k=8q+i][n=lo4]
  half8 bfrag;
#pragma unroll
  for (int i = 0; i < 8; ++i)
    bfrag[i] = (_Float16)h_init[(size_t)bg * HSZ + 8 * q + i];

  float e1[4], e2[4];  // relu'd state (fp32): units 8q+r / 8q+4+r, loop-carried

#define STEP(xv)                                                              \
  do {                                                                        \
    f32x4 c1, c2;                                                             \
    _Pragma("unroll") for (int r = 0; r < 4; ++r) {                           \
      c1[r] = fmaf((xv), wih1[r], bia1[r]);                                   \
      c2[r] = fmaf((xv), wih2[r], bia2[r]);                                   \
    }                                                                         \
    f32x4 d1 = __builtin_amdgcn_mfma_f32_16x16x32_f16(A1, bfrag, c1, 0, 0, 0);\
    f32x4 d2 = __builtin_amdgcn_mfma_f32_16x16x32_f16(A2, bfrag, c2, 0, 0, 0);\
    _Pragma("unroll") for (int r = 0; r < 4; ++r) {                           \
      e1[r] = fmaxf(d1[r], 0.f);                                              \
      e2[r] = fmaxf(d2[r], 0.f);                                              \
    }                                                                         \
    union { fp16x2 h2[4]; half8 h8; } cv;                                     \
    cv.h2[0] = __builtin_amdgcn_cvt_pkrtz(e1[0], e1[1]); /* units 8q+0,1 */   \
    cv.h2[1] = __builtin_amdgcn_cvt_pkrtz(e1[2], e1[3]); /* units 8q+2,3 */   \
    cv.h2[2] = __builtin_amdgcn_cvt_pkrtz(e2[0], e2[1]); /* units 8q+4,5 */   \
    cv.h2[3] = __builtin_amdgcn_cvt_pkrtz(e2[2], e2[3]); /* units 8q+6,7 */   \
    bfrag = cv.h8;                                                            \
  } while (0)

  // x feed: lane reads its batch's row; quads 4x redundant (L1 absorbs).
  // 2-deep float4 rotation = 8-step prefetch distance.
  const float4* xr = (const float4*)(x + (size_t)bg * (size_t)T);
  const int last = T / 4 - 1;
  float4 xa = xr[0], xb = xr[1];

#pragma unroll 1
  for (int t = 0; t < T; t += 8) {
    int i0 = (t >> 2) + 2; if (i0 > last) i0 = last;
    int i1 = (t >> 2) + 3; if (i1 > last) i1 = last;
    float4 na = xr[i0];
    float4 nb = xr[i1];
    STEP(xa.x); STEP(xa.y); STEP(xa.z); STEP(xa.w);
    STEP(xb.x); STEP(xb.y); STEP(xb.z); STEP(xb.w);
    xa = na; xb = nb;
  }

  // out[bg] = sum_u h[u]*W_reg[u] + b_reg; lane (q,n) holds units 8q+r (e1)
  // and 8q+4+r (e2) in fp32. Reduce across quads (lanes n, n+16, n+32, n+48).
  float v = 0.f;
#pragma unroll
  for (int r = 0; r < 4; ++r) {
    v = fmaf(e1[r], W_reg[8 * q + r], v);
    v = fmaf(e2[r], W_reg[8 * q + 4 + r], v);
  }
  v += __shfl_xor(v, 16, 64);
  v += __shfl_xor(v, 32, 64);
  if (q == 0) out[bg] = v + b_reg[0];
}

extern "C" void kernel_launch(void* const* d_in, const int* in_sizes, int n_in,
                              void* d_out, int out_size, void* d_ws, size_t ws_size,
                              hipStream_t stream) {
  const float* x      = (const float*)d_in[0];
  const float* h_init = (const float*)d_in[1];
  const float* W_ih   = (const float*)d_in[2];
  const float* W_hh   = (const float*)d_in[3];
  const float* b_ih   = (const float*)d_in[4];
  const float* b_hh   = (const float*)d_in[5];
  const float* W_reg  = (const float*)d_in[6];
  const float* b_reg  = (const float*)d_in[7];
  float* out = (float*)d_out;

  const int B = in_sizes[1] / HSZ;   // 4096
  const int T = in_sizes[0] / B;     // 4096
  const int grid = B / 16;           // 16 batches per wave/block

  rnn_reg_kernel<<<dim3(grid), dim3(64), 0, stream>>>(
      x, h_init, W_ih, W_hh, b_ih, b_hh, W_reg, b_reg, out, T);
}